// Round 11
// baseline (2528.905 us; speedup 1.0000x reference)
//
#include <hip/hip_runtime.h>

// GCN 2-layer forward, atomic-free aggregation via on-device CSR.
// x:[N,128] f32, edge_index:[2,E] int32, W1:[128,64], b1:[64], W2:[64,64], b2:[64]
//
// CSR build is two-phase to kill scatter write-amplification (round-8 lesson:
// one open 64B write frontier per NODE = 800KB dirty/XCD -> structural eviction
// of partial lines, 13x write amp; nt-load hints don't fix it):
//   Phase A: bin edges into 196 coarse buckets (512 dst nodes each), packed
//            (dlocal<<17|src) in u32. XCD-class partitioning (bucket&7) keeps
//            all writers of a bucket on one XCD; only ~24 open frontiers/XCD.
//   Phase B: one block per bucket: LDS histogram -> cnt; LDS cursors -> eidx.
//            Each block's eidx writes land in one contiguous L2-resident region.

#define FILL_CS 8192
#define BSH 9                   // 512 nodes per bucket
#define BCAP 9216               // mean 8192 edges/bucket + ~11 sigma margin

// Phase A: coarse bucket scatter, XCD-partitioned by bucket class.
__global__ __launch_bounds__(256) void k_bucket(const int* __restrict__ src,
                                                const int* __restrict__ dst,
                                                int* __restrict__ bcur,
                                                unsigned int* __restrict__ bkt,
                                                int E) {
  int r = blockIdx.x & 7;
  int base = (blockIdx.x >> 3) * FILL_CS;
  int end = base + FILL_CS;
  if (end > E) end = E;
  for (int e = base + threadIdx.x; e < end; e += 256) {
    int d = dst[e];
    int b = d >> BSH;
    if ((b & 7) == r) {
      int s = src[e];
      int p = atomicAdd(&bcur[b], 1);
      if (p < BCAP)
        bkt[(size_t)b * BCAP + p] = ((unsigned int)(d & 511) << 17) | (unsigned int)s;
    }
  }
}

// Phase B1: per-bucket LDS histogram -> cnt (writes every node in range, no memset).
__global__ __launch_bounds__(256) void k_bcount(const unsigned int* __restrict__ bkt,
                                                const int* __restrict__ bcur,
                                                int* __restrict__ cnt, int N) {
  __shared__ int lc[512];
  int b = blockIdx.x;
  lc[threadIdx.x] = 0;
  lc[threadIdx.x + 256] = 0;
  __syncthreads();
  int len = bcur[b];
  if (len > BCAP) len = BCAP;
  const unsigned int* bb = bkt + (size_t)b * BCAP;
  for (int i = threadIdx.x; i < len; i += 256)
    atomicAdd(&lc[bb[i] >> 17], 1);
  __syncthreads();
  int base = b << BSH;
#pragma unroll
  for (int k = 0; k < 2; ++k) {
    int i = threadIdx.x + k * 256;
    if (base + i < N) cnt[base + i] = lc[i];
  }
}

__global__ __launch_bounds__(256) void k_dinv(const int* __restrict__ cnt,
                                              float* __restrict__ dinv, int N) {
  int i = blockIdx.x * 256 + threadIdx.x;
  if (i < N) dinv[i] = rsqrtf((float)cnt[i] + 1.0f);  // self-loop adds 1
}

// ---- 3-kernel exclusive scan of cnt[N] -> row[N], block sums in bsum ----
__global__ __launch_bounds__(256) void k_scan1(const int* __restrict__ cnt,
                                               int* __restrict__ row,
                                               int* __restrict__ bsum, int N) {
  __shared__ int tmp[256];
  int i = blockIdx.x * 256 + threadIdx.x;
  int v = (i < N) ? cnt[i] : 0;
  tmp[threadIdx.x] = v;
  __syncthreads();
  for (int off = 1; off < 256; off <<= 1) {
    int t = (threadIdx.x >= off) ? tmp[threadIdx.x - off] : 0;
    __syncthreads();
    tmp[threadIdx.x] += t;
    __syncthreads();
  }
  if (i < N) row[i] = tmp[threadIdx.x] - v;  // exclusive
  if (threadIdx.x == 255) bsum[blockIdx.x] = tmp[255];
}

__global__ __launch_bounds__(512) void k_scan2(int* __restrict__ bsum, int nb) {
  __shared__ int tmp[512];
  int v = (threadIdx.x < nb) ? bsum[threadIdx.x] : 0;
  tmp[threadIdx.x] = v;
  __syncthreads();
  for (int off = 1; off < 512; off <<= 1) {
    int t = (threadIdx.x >= off) ? tmp[threadIdx.x - off] : 0;
    __syncthreads();
    tmp[threadIdx.x] += t;
    __syncthreads();
  }
  if (threadIdx.x < nb) bsum[threadIdx.x] = tmp[threadIdx.x] - v;  // exclusive
}

__global__ __launch_bounds__(256) void k_scan3(int* __restrict__ row,
                                               const int* __restrict__ bsum,
                                               int N, int E) {
  int i = blockIdx.x * 256 + threadIdx.x;
  if (i < N) row[i] += bsum[blockIdx.x];
  if (i == 0) row[N] = E;
}

// Phase B2: per-bucket fine fill. LDS cursors; eidx writes confined to the
// bucket's contiguous row-range (single block, single XCD, written once).
__global__ __launch_bounds__(256) void k_bfill(const unsigned int* __restrict__ bkt,
                                               const int* __restrict__ bcur,
                                               const int* __restrict__ row,
                                               int* __restrict__ eidx, int N) {
  __shared__ int fl[512];
  int b = blockIdx.x;
  fl[threadIdx.x] = 0;
  fl[threadIdx.x + 256] = 0;
  __syncthreads();
  int len = bcur[b];
  if (len > BCAP) len = BCAP;
  const unsigned int* bb = bkt + (size_t)b * BCAP;
  int base = b << BSH;
  for (int i = threadIdx.x; i < len; i += 256) {
    unsigned int v = bb[i];
    int dl = v >> 17;
    int s = v & 0x1FFFF;
    int ofs = atomicAdd(&fl[dl], 1);
    eidx[row[base + dl] + ofs] = s;
  }
}

// LDS-tiled GEMM: HS[node,j] = dinv[node] * sum_k X[node,k]*W[k,j].
// Block = 256 threads, tile = 64 nodes x 64 cols x full K in LDS.
// Each thread owns a 4x4 register tile (acc stays in VGPRs).
// History: acc[64]/thread -> scratch spill (VALUBusy 11%); per-lane VMEM W
// loads -> VMEM-issue bound (VALUBusy 5%). LDS staging fixes both.
template <int K>
__global__ __launch_bounds__(256) void k_gemm(const float* __restrict__ X,
                                              const float* __restrict__ W,
                                              const float* __restrict__ dinv,
                                              float* __restrict__ HS, int N) {
  __shared__ float Xs[64][K + 4];
  __shared__ float Ws[K][64];
  const int t = threadIdx.x;
  const int base = blockIdx.x * 64;

  for (int idx = t * 4; idx < 64 * K; idx += 1024) {
    int r = idx / K, c = idx % K;
    float4 v = make_float4(0.f, 0.f, 0.f, 0.f);
    if (base + r < N)
      v = *reinterpret_cast<const float4*>(X + (size_t)(base + r) * K + c);
    *reinterpret_cast<float4*>(&Xs[r][c]) = v;
  }
  for (int idx = t * 4; idx < K * 64; idx += 1024) {
    float4 v = *reinterpret_cast<const float4*>(W + idx);
    *reinterpret_cast<float4*>(&Ws[0][0] + idx) = v;
  }
  __syncthreads();

  const int n0 = (t >> 4) * 4;
  const int j0 = (t & 15) * 4;
  float acc[4][4];
#pragma unroll
  for (int i = 0; i < 4; ++i)
#pragma unroll
    for (int j = 0; j < 4; ++j) acc[i][j] = 0.f;

  for (int k0 = 0; k0 < K; k0 += 4) {
    float4 xv[4];
#pragma unroll
    for (int i = 0; i < 4; ++i)
      xv[i] = *reinterpret_cast<const float4*>(&Xs[n0 + i][k0]);
#pragma unroll
    for (int kk = 0; kk < 4; ++kk) {
      float4 wv = *reinterpret_cast<const float4*>(&Ws[k0 + kk][j0]);
#pragma unroll
      for (int i = 0; i < 4; ++i) {
        float xs = (kk == 0) ? xv[i].x : (kk == 1) ? xv[i].y
                 : (kk == 2) ? xv[i].z : xv[i].w;
        acc[i][0] = fmaf(xs, wv.x, acc[i][0]);
        acc[i][1] = fmaf(xs, wv.y, acc[i][1]);
        acc[i][2] = fmaf(xs, wv.z, acc[i][2]);
        acc[i][3] = fmaf(xs, wv.w, acc[i][3]);
      }
    }
  }

#pragma unroll
  for (int i = 0; i < 4; ++i) {
    int node = base + n0 + i;
    if (node < N) {
      float di = dinv[node];
      float4 o;
      o.x = acc[i][0] * di; o.y = acc[i][1] * di;
      o.z = acc[i][2] * di; o.w = acc[i][3] * di;
      *reinterpret_cast<float4*>(HS + (size_t)node * 64 + j0) = o;
    }
  }
}

// One wave per node, lane = feature. hs rows are pre-scaled by dinv[src]:
// out[d] = dinv[d]*(sum_{s in in(d)} hs[s] + hs[d]) + bias   (+relu)
__global__ __launch_bounds__(256) void k_agg(const float* __restrict__ hs,
                                             const int* __restrict__ row,
                                             const int* __restrict__ eidx,
                                             const float* __restrict__ dinv,
                                             const float* __restrict__ bias,
                                             float* __restrict__ out, int N,
                                             int relu) {
  int gid = blockIdx.x * 256 + threadIdx.x;
  int node = gid >> 6, lane = gid & 63;
  if (node >= N) return;
  int beg = row[node], end = row[node + 1];
  float a0 = 0.f, a1 = 0.f, a2 = 0.f, a3 = 0.f;
  int e = beg;
  for (; e + 3 < end; e += 4) {
    int s0 = eidx[e], s1 = eidx[e + 1], s2 = eidx[e + 2], s3 = eidx[e + 3];
    a0 += hs[(size_t)s0 * 64 + lane];
    a1 += hs[(size_t)s1 * 64 + lane];
    a2 += hs[(size_t)s2 * 64 + lane];
    a3 += hs[(size_t)s3 * 64 + lane];
  }
  for (; e < end; ++e) a0 += hs[(size_t)eidx[e] * 64 + lane];
  float dd = dinv[node];
  float v = dd * ((a0 + a1) + (a2 + a3) + hs[(size_t)node * 64 + lane]) + bias[lane];
  if (relu) v = fmaxf(v, 0.f);
  out[(size_t)node * 64 + lane] = v;
}

extern "C" void kernel_launch(void* const* d_in, const int* in_sizes, int n_in,
                              void* d_out, int out_size, void* d_ws, size_t ws_size,
                              hipStream_t stream) {
  const float* x  = (const float*)d_in[0];
  const int*   ei = (const int*)d_in[1];
  const float* W1 = (const float*)d_in[2];
  const float* b1 = (const float*)d_in[3];
  const float* W2 = (const float*)d_in[4];
  const float* b2 = (const float*)d_in[5];
  float* out = (float*)d_out;

  const int N = in_sizes[0] / 128;  // 100000
  const int E = in_sizes[1] / 2;    // 1600000
  const int* src = ei;
  const int* dstv = ei + E;

  const int nbuckets = (N + (1 << BSH) - 1) >> BSH;  // 196

  // workspace layout (4B units), ~40.5 MB total
  int*   cnt  = (int*)d_ws;                          // [N]
  int*   row  = cnt + 102400;                        // [N+1]
  float* dinv = (float*)(cnt + 204800);              // [N]
  int*   bsum = cnt + 307200;                        // [512]
  int*   bcur = cnt + 307712;                        // [nbuckets]
  int*   eidx = cnt + 308224;                        // [E]
  unsigned int* bkt = (unsigned int*)(cnt + 1908224);// [nbuckets*BCAP] ~7.2MB
  float* bufA = (float*)(cnt + 1908224 + 196 * BCAP);// [N*64]

  const int nb = (N + 255) / 256;
  const int ngemm = (N + 63) / 64;
  const int nchunk = (E + FILL_CS - 1) / FILL_CS;

  // ---- CSR build (shared by both convs) ----
  hipMemsetAsync(bcur, 0, (size_t)nbuckets * 4, stream);
  k_bucket<<<nchunk * 8, 256, 0, stream>>>(src, dstv, bcur, bkt, E);
  k_bcount<<<nbuckets, 256, 0, stream>>>(bkt, bcur, cnt, N);
  k_dinv<<<nb, 256, 0, stream>>>(cnt, dinv, N);
  k_scan1<<<nb, 256, 0, stream>>>(cnt, row, bsum, N);
  k_scan2<<<1, 512, 0, stream>>>(bsum, nb);
  k_scan3<<<nb, 256, 0, stream>>>(row, bsum, N, E);
  k_bfill<<<nbuckets, 256, 0, stream>>>(bkt, bcur, row, eidx, N);

  // ---- conv1: hs1 = dinv*(x@W1) -> agg -> relu -> d_out ----
  k_gemm<128><<<ngemm, 256, 0, stream>>>(x, W1, dinv, bufA, N);
  k_agg<<<(N * 64 + 255) / 256, 256, 0, stream>>>(bufA, row, eidx, dinv, b1, out, N, 1);

  // ---- conv2: hs2 = dinv*(out@W2) -> agg -> d_out ----
  k_gemm<64><<<ngemm, 256, 0, stream>>>(out, W2, dinv, bufA, N);
  k_agg<<<(N * 64 + 255) / 256, 256, 0, stream>>>(bufA, row, eidx, dinv, b2, out, N, 0);
}

// Round 12
// 385.098 us; speedup vs baseline: 6.5669x; 6.5669x over previous
//
#include <hip/hip_runtime.h>

// GCN 2-layer forward, atomic-free aggregation via on-device CSR.
// x:[N,128] f32, edge_index:[2,E] int32, W1:[128,64], b1:[64], W2:[64,64], b2:[64]
//
// CSR build lessons:
//  r2:  per-element f32 atomics on agg -> 1.8GB L2 RMW traffic (90% of runtime).
//  r7:  per-node scatter cursors -> 13x write amp (12.5K open frontiers/XCD).
//  r8:  nt-load hints don't fix frontier eviction.
//  r11: 196 shared atomic cursors -> serialization + cross-XCD false sharing,
//       2168us. Counter contention ~ E/counters; never funnel E ops through
//       O(100) global cursors.
// => deterministic 3-pass radix binning: NO global atomics anywhere.
//    P1 k_hist:  per-chunk LDS histogram over 196 buckets -> hist[c][b]
//    P2 k_choff: per-bucket scan over chunks -> choff[c][b], total[b]
//       k_bbase: scan total -> bbase[b] (bucket base in bkt)
//    P3 k_fill3: re-read chunk, LDS cursors = bbase+choff, write bkt packed
//       (dlocal<<17|src). Then per-bucket: k_bcount (LDS hist -> cnt),
//       k_bfill (LDS cursors -> eidx, contiguous region per block).
// Assumes nchunk<=256 and nbkt<=256 (196/196 for N=100K, E=1.6M).

#define FILL_CS 8192
#define BSH 9                   // 512 nodes per bucket

// P1: per-chunk histogram (LDS atomics only).
__global__ __launch_bounds__(256) void k_hist(const int* __restrict__ dst,
                                              int* __restrict__ hist,
                                              int E, int nbkt) {
  __shared__ int lc[256];
  int c = blockIdx.x;
  lc[threadIdx.x] = 0;
  __syncthreads();
  int base = c * FILL_CS;
  int end = base + FILL_CS;
  if (end > E) end = E;
  for (int e = base + threadIdx.x; e < end; e += 256)
    atomicAdd(&lc[dst[e] >> BSH], 1);
  __syncthreads();
  if (threadIdx.x < nbkt) hist[c * nbkt + threadIdx.x] = lc[threadIdx.x];
}

// P2a: one block per bucket; exclusive scan of hist[.][b] over chunks.
__global__ __launch_bounds__(256) void k_choff(const int* __restrict__ hist,
                                               int* __restrict__ choff,
                                               int* __restrict__ total,
                                               int nchunk, int nbkt) {
  __shared__ int tmp[256];
  int b = blockIdx.x;
  int c = threadIdx.x;
  int v = (c < nchunk) ? hist[c * nbkt + b] : 0;
  tmp[c] = v;
  __syncthreads();
  for (int off = 1; off < 256; off <<= 1) {
    int t = (c >= off) ? tmp[c - off] : 0;
    __syncthreads();
    tmp[c] += t;
    __syncthreads();
  }
  if (c < nchunk) choff[c * nbkt + b] = tmp[c] - v;  // exclusive
  if (c == 255) total[b] = tmp[255];
}

// P2b: single block; exclusive scan of total -> bbase; bbase[nbkt]=E.
__global__ __launch_bounds__(256) void k_bbase(const int* __restrict__ total,
                                               int* __restrict__ bbase,
                                               int nbkt, int E) {
  __shared__ int tmp[256];
  int i = threadIdx.x;
  int v = (i < nbkt) ? total[i] : 0;
  tmp[i] = v;
  __syncthreads();
  for (int off = 1; off < 256; off <<= 1) {
    int t = (i >= off) ? tmp[i - off] : 0;
    __syncthreads();
    tmp[i] += t;
    __syncthreads();
  }
  if (i < nbkt) bbase[i] = tmp[i] - v;
  if (i == 0) bbase[nbkt] = E;
}

// P3: deterministic bucket scatter; only LDS atomics.
__global__ __launch_bounds__(256) void k_fill3(const int* __restrict__ src,
                                               const int* __restrict__ dst,
                                               const int* __restrict__ choff,
                                               const int* __restrict__ bbase,
                                               unsigned int* __restrict__ bkt,
                                               int E, int nbkt) {
  __shared__ int cur[256];
  int c = blockIdx.x;
  if (threadIdx.x < nbkt)
    cur[threadIdx.x] = bbase[threadIdx.x] + choff[c * nbkt + threadIdx.x];
  __syncthreads();
  int base = c * FILL_CS;
  int end = base + FILL_CS;
  if (end > E) end = E;
  for (int e = base + threadIdx.x; e < end; e += 256) {
    int d = dst[e];
    int s = src[e];
    int p = atomicAdd(&cur[d >> BSH], 1);
    bkt[p] = ((unsigned int)(d & 511) << 17) | (unsigned int)s;
  }
}

// Per-bucket LDS histogram -> cnt (covers every node; no memset needed).
__global__ __launch_bounds__(256) void k_bcount(const unsigned int* __restrict__ bkt,
                                                const int* __restrict__ bbase,
                                                int* __restrict__ cnt, int N) {
  __shared__ int lc[512];
  int b = blockIdx.x;
  lc[threadIdx.x] = 0;
  lc[threadIdx.x + 256] = 0;
  __syncthreads();
  int beg = bbase[b], end = bbase[b + 1];
  for (int i = beg + threadIdx.x; i < end; i += 256)
    atomicAdd(&lc[bkt[i] >> 17], 1);
  __syncthreads();
  int base = b << BSH;
#pragma unroll
  for (int k = 0; k < 2; ++k) {
    int i = threadIdx.x + k * 256;
    if (base + i < N) cnt[base + i] = lc[i];
  }
}

__global__ __launch_bounds__(256) void k_dinv(const int* __restrict__ cnt,
                                              float* __restrict__ dinv, int N) {
  int i = blockIdx.x * 256 + threadIdx.x;
  if (i < N) dinv[i] = rsqrtf((float)cnt[i] + 1.0f);  // self-loop adds 1
}

// ---- 3-kernel exclusive scan of cnt[N] -> row[N], block sums in bsum ----
__global__ __launch_bounds__(256) void k_scan1(const int* __restrict__ cnt,
                                               int* __restrict__ row,
                                               int* __restrict__ bsum, int N) {
  __shared__ int tmp[256];
  int i = blockIdx.x * 256 + threadIdx.x;
  int v = (i < N) ? cnt[i] : 0;
  tmp[threadIdx.x] = v;
  __syncthreads();
  for (int off = 1; off < 256; off <<= 1) {
    int t = (threadIdx.x >= off) ? tmp[threadIdx.x - off] : 0;
    __syncthreads();
    tmp[threadIdx.x] += t;
    __syncthreads();
  }
  if (i < N) row[i] = tmp[threadIdx.x] - v;  // exclusive
  if (threadIdx.x == 255) bsum[blockIdx.x] = tmp[255];
}

__global__ __launch_bounds__(512) void k_scan2(int* __restrict__ bsum, int nb) {
  __shared__ int tmp[512];
  int v = (threadIdx.x < nb) ? bsum[threadIdx.x] : 0;
  tmp[threadIdx.x] = v;
  __syncthreads();
  for (int off = 1; off < 512; off <<= 1) {
    int t = (threadIdx.x >= off) ? tmp[threadIdx.x - off] : 0;
    __syncthreads();
    tmp[threadIdx.x] += t;
    __syncthreads();
  }
  if (threadIdx.x < nb) bsum[threadIdx.x] = tmp[threadIdx.x] - v;  // exclusive
}

__global__ __launch_bounds__(256) void k_scan3(int* __restrict__ row,
                                               const int* __restrict__ bsum,
                                               int N, int E) {
  int i = blockIdx.x * 256 + threadIdx.x;
  if (i < N) row[i] += bsum[blockIdx.x];
  if (i == 0) row[N] = E;
}

// Per-bucket fine fill: LDS cursors; eidx writes confined to the bucket's
// contiguous row-range (single block, single XCD, written once).
__global__ __launch_bounds__(256) void k_bfill(const unsigned int* __restrict__ bkt,
                                               const int* __restrict__ bbase,
                                               const int* __restrict__ row,
                                               int* __restrict__ eidx, int N) {
  __shared__ int fl[512];
  int b = blockIdx.x;
  fl[threadIdx.x] = 0;
  fl[threadIdx.x + 256] = 0;
  __syncthreads();
  int beg = bbase[b], end = bbase[b + 1];
  int base = b << BSH;
  for (int i = beg + threadIdx.x; i < end; i += 256) {
    unsigned int v = bkt[i];
    int dl = v >> 17;
    int s = v & 0x1FFFF;
    int ofs = atomicAdd(&fl[dl], 1);
    eidx[row[base + dl] + ofs] = s;
  }
}

// LDS-tiled GEMM: HS[node,j] = dinv[node] * sum_k X[node,k]*W[k,j].
// Block = 256 threads, tile = 64 nodes x 64 cols x full K in LDS.
// Each thread owns a 4x4 register tile (acc stays in VGPRs).
// History: acc[64]/thread -> scratch spill (VALUBusy 11%); per-lane VMEM W
// loads -> VMEM-issue bound (VALUBusy 5%). LDS staging fixes both.
template <int K>
__global__ __launch_bounds__(256) void k_gemm(const float* __restrict__ X,
                                              const float* __restrict__ W,
                                              const float* __restrict__ dinv,
                                              float* __restrict__ HS, int N) {
  __shared__ float Xs[64][K + 4];
  __shared__ float Ws[K][64];
  const int t = threadIdx.x;
  const int base = blockIdx.x * 64;

  for (int idx = t * 4; idx < 64 * K; idx += 1024) {
    int r = idx / K, c = idx % K;
    float4 v = make_float4(0.f, 0.f, 0.f, 0.f);
    if (base + r < N)
      v = *reinterpret_cast<const float4*>(X + (size_t)(base + r) * K + c);
    *reinterpret_cast<float4*>(&Xs[r][c]) = v;
  }
  for (int idx = t * 4; idx < K * 64; idx += 1024) {
    float4 v = *reinterpret_cast<const float4*>(W + idx);
    *reinterpret_cast<float4*>(&Ws[0][0] + idx) = v;
  }
  __syncthreads();

  const int n0 = (t >> 4) * 4;
  const int j0 = (t & 15) * 4;
  float acc[4][4];
#pragma unroll
  for (int i = 0; i < 4; ++i)
#pragma unroll
    for (int j = 0; j < 4; ++j) acc[i][j] = 0.f;

  for (int k0 = 0; k0 < K; k0 += 4) {
    float4 xv[4];
#pragma unroll
    for (int i = 0; i < 4; ++i)
      xv[i] = *reinterpret_cast<const float4*>(&Xs[n0 + i][k0]);
#pragma unroll
    for (int kk = 0; kk < 4; ++kk) {
      float4 wv = *reinterpret_cast<const float4*>(&Ws[k0 + kk][j0]);
#pragma unroll
      for (int i = 0; i < 4; ++i) {
        float xs = (kk == 0) ? xv[i].x : (kk == 1) ? xv[i].y
                 : (kk == 2) ? xv[i].z : xv[i].w;
        acc[i][0] = fmaf(xs, wv.x, acc[i][0]);
        acc[i][1] = fmaf(xs, wv.y, acc[i][1]);
        acc[i][2] = fmaf(xs, wv.z, acc[i][2]);
        acc[i][3] = fmaf(xs, wv.w, acc[i][3]);
      }
    }
  }

#pragma unroll
  for (int i = 0; i < 4; ++i) {
    int node = base + n0 + i;
    if (node < N) {
      float di = dinv[node];
      float4 o;
      o.x = acc[i][0] * di; o.y = acc[i][1] * di;
      o.z = acc[i][2] * di; o.w = acc[i][3] * di;
      *reinterpret_cast<float4*>(HS + (size_t)node * 64 + j0) = o;
    }
  }
}

// One wave per node, lane = feature. hs rows are pre-scaled by dinv[src]:
// out[d] = dinv[d]*(sum_{s in in(d)} hs[s] + hs[d]) + bias   (+relu)
__global__ __launch_bounds__(256) void k_agg(const float* __restrict__ hs,
                                             const int* __restrict__ row,
                                             const int* __restrict__ eidx,
                                             const float* __restrict__ dinv,
                                             const float* __restrict__ bias,
                                             float* __restrict__ out, int N,
                                             int relu) {
  int gid = blockIdx.x * 256 + threadIdx.x;
  int node = gid >> 6, lane = gid & 63;
  if (node >= N) return;
  int beg = row[node], end = row[node + 1];
  float a0 = 0.f, a1 = 0.f, a2 = 0.f, a3 = 0.f;
  int e = beg;
  for (; e + 3 < end; e += 4) {
    int s0 = eidx[e], s1 = eidx[e + 1], s2 = eidx[e + 2], s3 = eidx[e + 3];
    a0 += hs[(size_t)s0 * 64 + lane];
    a1 += hs[(size_t)s1 * 64 + lane];
    a2 += hs[(size_t)s2 * 64 + lane];
    a3 += hs[(size_t)s3 * 64 + lane];
  }
  for (; e < end; ++e) a0 += hs[(size_t)eidx[e] * 64 + lane];
  float dd = dinv[node];
  float v = dd * ((a0 + a1) + (a2 + a3) + hs[(size_t)node * 64 + lane]) + bias[lane];
  if (relu) v = fmaxf(v, 0.f);
  out[(size_t)node * 64 + lane] = v;
}

extern "C" void kernel_launch(void* const* d_in, const int* in_sizes, int n_in,
                              void* d_out, int out_size, void* d_ws, size_t ws_size,
                              hipStream_t stream) {
  const float* x  = (const float*)d_in[0];
  const int*   ei = (const int*)d_in[1];
  const float* W1 = (const float*)d_in[2];
  const float* b1 = (const float*)d_in[3];
  const float* W2 = (const float*)d_in[4];
  const float* b2 = (const float*)d_in[5];
  float* out = (float*)d_out;

  const int N = in_sizes[0] / 128;  // 100000
  const int E = in_sizes[1] / 2;    // 1600000
  const int* src = ei;
  const int* dstv = ei + E;

  const int nbkt = (N + (1 << BSH) - 1) >> BSH;        // 196
  const int nchunk = (E + FILL_CS - 1) / FILL_CS;      // 196

  // workspace layout (4B units), ~33.5 MB total
  int*   cnt   = (int*)d_ws;                  // [N]
  int*   row   = cnt + 102400;                // [N+1]
  float* dinv  = (float*)(cnt + 205056);      // [N]
  int*   bsum  = cnt + 307456;                // [512]
  int*   hist  = cnt + 307968;                // [nchunk*nbkt]
  int*   choff = cnt + 346624;                // [nchunk*nbkt]
  int*   total = cnt + 385280;                // [nbkt]
  int*   bbase = cnt + 385536;                // [nbkt+1]
  unsigned int* bkt = (unsigned int*)(cnt + 385792);  // [E]
  int*   eidx  = cnt + 1985792;               // [E]
  float* bufA  = (float*)(cnt + 3585792);     // [N*64], 16B-aligned

  const int nb = (N + 255) / 256;
  const int ngemm = (N + 63) / 64;

  // ---- CSR build (deterministic, no global atomics) ----
  k_hist<<<nchunk, 256, 0, stream>>>(dstv, hist, E, nbkt);
  k_choff<<<nbkt, 256, 0, stream>>>(hist, choff, total, nchunk, nbkt);
  k_bbase<<<1, 256, 0, stream>>>(total, bbase, nbkt, E);
  k_fill3<<<nchunk, 256, 0, stream>>>(src, dstv, choff, bbase, bkt, E, nbkt);
  k_bcount<<<nbkt, 256, 0, stream>>>(bkt, bbase, cnt, N);
  k_dinv<<<nb, 256, 0, stream>>>(cnt, dinv, N);
  k_scan1<<<nb, 256, 0, stream>>>(cnt, row, bsum, N);
  k_scan2<<<1, 512, 0, stream>>>(bsum, nb);
  k_scan3<<<nb, 256, 0, stream>>>(row, bsum, N, E);
  k_bfill<<<nbkt, 256, 0, stream>>>(bkt, bbase, row, eidx, N);

  // ---- conv1: hs1 = dinv*(x@W1) -> agg -> relu -> d_out ----
  k_gemm<128><<<ngemm, 256, 0, stream>>>(x, W1, dinv, bufA, N);
  k_agg<<<(N * 64 + 255) / 256, 256, 0, stream>>>(bufA, row, eidx, dinv, b1, out, N, 1);

  // ---- conv2: hs2 = dinv*(out@W2) -> agg -> d_out ----
  k_gemm<64><<<ngemm, 256, 0, stream>>>(out, W2, dinv, bufA, N);
  k_agg<<<(N * 64 + 255) / 256, 256, 0, stream>>>(bufA, row, eidx, dinv, b2, out, N, 0);
}

// Round 13
// 360.997 us; speedup vs baseline: 7.0053x; 1.0668x over previous
//
#include <hip/hip_runtime.h>

// GCN 2-layer forward, atomic-free aggregation via on-device CSR.
// x:[N,128] f32, edge_index:[2,E] int32, W1:[128,64], b1:[64], W2:[64,64], b2:[64]
//
// CSR build lessons:
//  r2:  per-element f32 atomics on agg -> 1.8GB L2 RMW traffic (90% of runtime).
//  r7:  per-node scatter cursors -> 13x write amp (12.5K open frontiers/XCD).
//  r8:  nt-load hints don't fix frontier eviction.
//  r11: 196 shared atomic cursors -> serialization + cross-XCD false sharing.
//  r12: deterministic 3-pass radix binning (below) fixed the build; k_agg was
//       then latency-bound (VALUBusy 29%, HBM 37%, occ 69% - nothing saturated,
//       1KB in flight/wave). Fix: 16 thr/node, float4 lanes, 4-way unroll.

#define FILL_CS 8192
#define BSH 9                   // 512 nodes per bucket

// P1: per-chunk histogram (LDS atomics only).
__global__ __launch_bounds__(256) void k_hist(const int* __restrict__ dst,
                                              int* __restrict__ hist,
                                              int E, int nbkt) {
  __shared__ int lc[256];
  int c = blockIdx.x;
  lc[threadIdx.x] = 0;
  __syncthreads();
  int base = c * FILL_CS;
  int end = base + FILL_CS;
  if (end > E) end = E;
  for (int e = base + threadIdx.x; e < end; e += 256)
    atomicAdd(&lc[dst[e] >> BSH], 1);
  __syncthreads();
  if (threadIdx.x < nbkt) hist[c * nbkt + threadIdx.x] = lc[threadIdx.x];
}

// P2a: one block per bucket; exclusive scan of hist[.][b] over chunks.
__global__ __launch_bounds__(256) void k_choff(const int* __restrict__ hist,
                                               int* __restrict__ choff,
                                               int* __restrict__ total,
                                               int nchunk, int nbkt) {
  __shared__ int tmp[256];
  int b = blockIdx.x;
  int c = threadIdx.x;
  int v = (c < nchunk) ? hist[c * nbkt + b] : 0;
  tmp[c] = v;
  __syncthreads();
  for (int off = 1; off < 256; off <<= 1) {
    int t = (c >= off) ? tmp[c - off] : 0;
    __syncthreads();
    tmp[c] += t;
    __syncthreads();
  }
  if (c < nchunk) choff[c * nbkt + b] = tmp[c] - v;  // exclusive
  if (c == 255) total[b] = tmp[255];
}

// P2b: single block; exclusive scan of total -> bbase; bbase[nbkt]=E.
__global__ __launch_bounds__(256) void k_bbase(const int* __restrict__ total,
                                               int* __restrict__ bbase,
                                               int nbkt, int E) {
  __shared__ int tmp[256];
  int i = threadIdx.x;
  int v = (i < nbkt) ? total[i] : 0;
  tmp[i] = v;
  __syncthreads();
  for (int off = 1; off < 256; off <<= 1) {
    int t = (i >= off) ? tmp[i - off] : 0;
    __syncthreads();
    tmp[i] += t;
    __syncthreads();
  }
  if (i < nbkt) bbase[i] = tmp[i] - v;
  if (i == 0) bbase[nbkt] = E;
}

// P3: deterministic bucket scatter; only LDS atomics.
__global__ __launch_bounds__(256) void k_fill3(const int* __restrict__ src,
                                               const int* __restrict__ dst,
                                               const int* __restrict__ choff,
                                               const int* __restrict__ bbase,
                                               unsigned int* __restrict__ bkt,
                                               int E, int nbkt) {
  __shared__ int cur[256];
  int c = blockIdx.x;
  if (threadIdx.x < nbkt)
    cur[threadIdx.x] = bbase[threadIdx.x] + choff[c * nbkt + threadIdx.x];
  __syncthreads();
  int base = c * FILL_CS;
  int end = base + FILL_CS;
  if (end > E) end = E;
  for (int e = base + threadIdx.x; e < end; e += 256) {
    int d = dst[e];
    int s = src[e];
    int p = atomicAdd(&cur[d >> BSH], 1);
    bkt[p] = ((unsigned int)(d & 511) << 17) | (unsigned int)s;
  }
}

// Per-bucket LDS histogram -> cnt (covers every node; no memset needed).
__global__ __launch_bounds__(256) void k_bcount(const unsigned int* __restrict__ bkt,
                                                const int* __restrict__ bbase,
                                                int* __restrict__ cnt, int N) {
  __shared__ int lc[512];
  int b = blockIdx.x;
  lc[threadIdx.x] = 0;
  lc[threadIdx.x + 256] = 0;
  __syncthreads();
  int beg = bbase[b], end = bbase[b + 1];
  for (int i = beg + threadIdx.x; i < end; i += 256)
    atomicAdd(&lc[bkt[i] >> 17], 1);
  __syncthreads();
  int base = b << BSH;
#pragma unroll
  for (int k = 0; k < 2; ++k) {
    int i = threadIdx.x + k * 256;
    if (base + i < N) cnt[base + i] = lc[i];
  }
}

__global__ __launch_bounds__(256) void k_dinv(const int* __restrict__ cnt,
                                              float* __restrict__ dinv, int N) {
  int i = blockIdx.x * 256 + threadIdx.x;
  if (i < N) dinv[i] = rsqrtf((float)cnt[i] + 1.0f);  // self-loop adds 1
}

// ---- 3-kernel exclusive scan of cnt[N] -> row[N], block sums in bsum ----
__global__ __launch_bounds__(256) void k_scan1(const int* __restrict__ cnt,
                                               int* __restrict__ row,
                                               int* __restrict__ bsum, int N) {
  __shared__ int tmp[256];
  int i = blockIdx.x * 256 + threadIdx.x;
  int v = (i < N) ? cnt[i] : 0;
  tmp[threadIdx.x] = v;
  __syncthreads();
  for (int off = 1; off < 256; off <<= 1) {
    int t = (threadIdx.x >= off) ? tmp[threadIdx.x - off] : 0;
    __syncthreads();
    tmp[threadIdx.x] += t;
    __syncthreads();
  }
  if (i < N) row[i] = tmp[threadIdx.x] - v;  // exclusive
  if (threadIdx.x == 255) bsum[blockIdx.x] = tmp[255];
}

__global__ __launch_bounds__(512) void k_scan2(int* __restrict__ bsum, int nb) {
  __shared__ int tmp[512];
  int v = (threadIdx.x < nb) ? bsum[threadIdx.x] : 0;
  tmp[threadIdx.x] = v;
  __syncthreads();
  for (int off = 1; off < 512; off <<= 1) {
    int t = (threadIdx.x >= off) ? tmp[threadIdx.x - off] : 0;
    __syncthreads();
    tmp[threadIdx.x] += t;
    __syncthreads();
  }
  if (threadIdx.x < nb) bsum[threadIdx.x] = tmp[threadIdx.x] - v;  // exclusive
}

__global__ __launch_bounds__(256) void k_scan3(int* __restrict__ row,
                                               const int* __restrict__ bsum,
                                               int N, int E) {
  int i = blockIdx.x * 256 + threadIdx.x;
  if (i < N) row[i] += bsum[blockIdx.x];
  if (i == 0) row[N] = E;
}

// Per-bucket fine fill: LDS cursors; eidx writes confined to the bucket's
// contiguous row-range (single block, single XCD, written once).
__global__ __launch_bounds__(256) void k_bfill(const unsigned int* __restrict__ bkt,
                                               const int* __restrict__ bbase,
                                               const int* __restrict__ row,
                                               int* __restrict__ eidx, int N) {
  __shared__ int fl[512];
  int b = blockIdx.x;
  fl[threadIdx.x] = 0;
  fl[threadIdx.x + 256] = 0;
  __syncthreads();
  int beg = bbase[b], end = bbase[b + 1];
  int base = b << BSH;
  for (int i = beg + threadIdx.x; i < end; i += 256) {
    unsigned int v = bkt[i];
    int dl = v >> 17;
    int s = v & 0x1FFFF;
    int ofs = atomicAdd(&fl[dl], 1);
    eidx[row[base + dl] + ofs] = s;
  }
}

// LDS-tiled GEMM: HS[node,j] = dinv[node] * sum_k X[node,k]*W[k,j].
// Block = 256 threads, tile = 64 nodes x 64 cols x full K in LDS.
// Each thread owns a 4x4 register tile (acc stays in VGPRs).
// History: acc[64]/thread -> scratch spill (VALUBusy 11%); per-lane VMEM W
// loads -> VMEM-issue bound (VALUBusy 5%). LDS staging fixes both.
template <int K>
__global__ __launch_bounds__(256) void k_gemm(const float* __restrict__ X,
                                              const float* __restrict__ W,
                                              const float* __restrict__ dinv,
                                              float* __restrict__ HS, int N) {
  __shared__ float Xs[64][K + 4];
  __shared__ float Ws[K][64];
  const int t = threadIdx.x;
  const int base = blockIdx.x * 64;

  for (int idx = t * 4; idx < 64 * K; idx += 1024) {
    int r = idx / K, c = idx % K;
    float4 v = make_float4(0.f, 0.f, 0.f, 0.f);
    if (base + r < N)
      v = *reinterpret_cast<const float4*>(X + (size_t)(base + r) * K + c);
    *reinterpret_cast<float4*>(&Xs[r][c]) = v;
  }
  for (int idx = t * 4; idx < K * 64; idx += 1024) {
    float4 v = *reinterpret_cast<const float4*>(W + idx);
    *reinterpret_cast<float4*>(&Ws[0][0] + idx) = v;
  }
  __syncthreads();

  const int n0 = (t >> 4) * 4;
  const int j0 = (t & 15) * 4;
  float acc[4][4];
#pragma unroll
  for (int i = 0; i < 4; ++i)
#pragma unroll
    for (int j = 0; j < 4; ++j) acc[i][j] = 0.f;

  for (int k0 = 0; k0 < K; k0 += 4) {
    float4 xv[4];
#pragma unroll
    for (int i = 0; i < 4; ++i)
      xv[i] = *reinterpret_cast<const float4*>(&Xs[n0 + i][k0]);
#pragma unroll
    for (int kk = 0; kk < 4; ++kk) {
      float4 wv = *reinterpret_cast<const float4*>(&Ws[k0 + kk][j0]);
#pragma unroll
      for (int i = 0; i < 4; ++i) {
        float xs = (kk == 0) ? xv[i].x : (kk == 1) ? xv[i].y
                 : (kk == 2) ? xv[i].z : xv[i].w;
        acc[i][0] = fmaf(xs, wv.x, acc[i][0]);
        acc[i][1] = fmaf(xs, wv.y, acc[i][1]);
        acc[i][2] = fmaf(xs, wv.z, acc[i][2]);
        acc[i][3] = fmaf(xs, wv.w, acc[i][3]);
      }
    }
  }

#pragma unroll
  for (int i = 0; i < 4; ++i) {
    int node = base + n0 + i;
    if (node < N) {
      float di = dinv[node];
      float4 o;
      o.x = acc[i][0] * di; o.y = acc[i][1] * di;
      o.z = acc[i][2] * di; o.w = acc[i][3] * di;
      *reinterpret_cast<float4*>(HS + (size_t)node * 64 + j0) = o;
    }
  }
}

// Aggregation: 16 threads per node (4 nodes/wave), lane owns a float4 feature
// slice. 4-way edge unroll -> 4 independent float4 loads in flight per lane
// (4KB/wave vs 1KB in the 1-node/wave version, which was latency-bound:
// VALUBusy 29%, fetch BW 37%, occupancy 69% - nothing saturated).
// hs rows are pre-scaled by dinv[src]:
// out[d] = dinv[d]*(sum_{s in in(d)} hs[s] + hs[d]) + bias   (+relu)
__global__ __launch_bounds__(256) void k_agg(const float* __restrict__ hs,
                                             const int* __restrict__ row,
                                             const int* __restrict__ eidx,
                                             const float* __restrict__ dinv,
                                             const float* __restrict__ bias,
                                             float* __restrict__ out, int N,
                                             int relu) {
  int gid = blockIdx.x * 256 + threadIdx.x;
  int node = gid >> 4;
  if (node >= N) return;
  int q = (gid & 15) * 4;
  int beg = row[node], end = row[node + 1];
  float4 a0 = make_float4(0.f, 0.f, 0.f, 0.f);
  float4 a1 = make_float4(0.f, 0.f, 0.f, 0.f);
  float4 a2 = make_float4(0.f, 0.f, 0.f, 0.f);
  float4 a3 = make_float4(0.f, 0.f, 0.f, 0.f);
  int e = beg;
  for (; e + 3 < end; e += 4) {
    int s0 = eidx[e], s1 = eidx[e + 1], s2 = eidx[e + 2], s3 = eidx[e + 3];
    float4 v0 = *reinterpret_cast<const float4*>(hs + (size_t)s0 * 64 + q);
    float4 v1 = *reinterpret_cast<const float4*>(hs + (size_t)s1 * 64 + q);
    float4 v2 = *reinterpret_cast<const float4*>(hs + (size_t)s2 * 64 + q);
    float4 v3 = *reinterpret_cast<const float4*>(hs + (size_t)s3 * 64 + q);
    a0.x += v0.x; a0.y += v0.y; a0.z += v0.z; a0.w += v0.w;
    a1.x += v1.x; a1.y += v1.y; a1.z += v1.z; a1.w += v1.w;
    a2.x += v2.x; a2.y += v2.y; a2.z += v2.z; a2.w += v2.w;
    a3.x += v3.x; a3.y += v3.y; a3.z += v3.z; a3.w += v3.w;
  }
  for (; e < end; ++e) {
    int s = eidx[e];
    float4 v = *reinterpret_cast<const float4*>(hs + (size_t)s * 64 + q);
    a0.x += v.x; a0.y += v.y; a0.z += v.z; a0.w += v.w;
  }
  float4 self = *reinterpret_cast<const float4*>(hs + (size_t)node * 64 + q);
  float4 bv = *reinterpret_cast<const float4*>(bias + q);
  float dd = dinv[node];
  float4 r;
  r.x = dd * (a0.x + a1.x + a2.x + a3.x + self.x) + bv.x;
  r.y = dd * (a0.y + a1.y + a2.y + a3.y + self.y) + bv.y;
  r.z = dd * (a0.z + a1.z + a2.z + a3.z + self.z) + bv.z;
  r.w = dd * (a0.w + a1.w + a2.w + a3.w + self.w) + bv.w;
  if (relu) {
    r.x = fmaxf(r.x, 0.f); r.y = fmaxf(r.y, 0.f);
    r.z = fmaxf(r.z, 0.f); r.w = fmaxf(r.w, 0.f);
  }
  *reinterpret_cast<float4*>(out + (size_t)node * 64 + q) = r;
}

extern "C" void kernel_launch(void* const* d_in, const int* in_sizes, int n_in,
                              void* d_out, int out_size, void* d_ws, size_t ws_size,
                              hipStream_t stream) {
  const float* x  = (const float*)d_in[0];
  const int*   ei = (const int*)d_in[1];
  const float* W1 = (const float*)d_in[2];
  const float* b1 = (const float*)d_in[3];
  const float* W2 = (const float*)d_in[4];
  const float* b2 = (const float*)d_in[5];
  float* out = (float*)d_out;

  const int N = in_sizes[0] / 128;  // 100000
  const int E = in_sizes[1] / 2;    // 1600000
  const int* src = ei;
  const int* dstv = ei + E;

  const int nbkt = (N + (1 << BSH) - 1) >> BSH;        // 196
  const int nchunk = (E + FILL_CS - 1) / FILL_CS;      // 196

  // workspace layout (4B units), ~40 MB total
  int*   cnt   = (int*)d_ws;                  // [N]
  int*   row   = cnt + 102400;                // [N+1]
  float* dinv  = (float*)(cnt + 205056);      // [N]
  int*   bsum  = cnt + 307456;                // [512]
  int*   hist  = cnt + 307968;                // [nchunk*nbkt]
  int*   choff = cnt + 346624;                // [nchunk*nbkt]
  int*   total = cnt + 385280;                // [nbkt]
  int*   bbase = cnt + 385536;                // [nbkt+1]
  unsigned int* bkt = (unsigned int*)(cnt + 385792);  // [E]
  int*   eidx  = cnt + 1985792;               // [E]
  float* bufA  = (float*)(cnt + 3585792);     // [N*64], 16B-aligned

  const int nb = (N + 255) / 256;
  const int ngemm = (N + 63) / 64;
  const int nagg = (N * 16 + 255) / 256;

  // ---- CSR build (deterministic, no global atomics) ----
  k_hist<<<nchunk, 256, 0, stream>>>(dstv, hist, E, nbkt);
  k_choff<<<nbkt, 256, 0, stream>>>(hist, choff, total, nchunk, nbkt);
  k_bbase<<<1, 256, 0, stream>>>(total, bbase, nbkt, E);
  k_fill3<<<nchunk, 256, 0, stream>>>(src, dstv, choff, bbase, bkt, E, nbkt);
  k_bcount<<<nbkt, 256, 0, stream>>>(bkt, bbase, cnt, N);
  k_dinv<<<nb, 256, 0, stream>>>(cnt, dinv, N);
  k_scan1<<<nb, 256, 0, stream>>>(cnt, row, bsum, N);
  k_scan2<<<1, 512, 0, stream>>>(bsum, nb);
  k_scan3<<<nb, 256, 0, stream>>>(row, bsum, N, E);
  k_bfill<<<nbkt, 256, 0, stream>>>(bkt, bbase, row, eidx, N);

  // ---- conv1: hs1 = dinv*(x@W1) -> agg -> relu -> d_out ----
  k_gemm<128><<<ngemm, 256, 0, stream>>>(x, W1, dinv, bufA, N);
  k_agg<<<nagg, 256, 0, stream>>>(bufA, row, eidx, dinv, b1, out, N, 1);

  // ---- conv2: hs2 = dinv*(out@W2) -> agg -> d_out ----
  k_gemm<64><<<ngemm, 256, 0, stream>>>(out, W2, dinv, bufA, N);
  k_agg<<<nagg, 256, 0, stream>>>(bufA, row, eidx, dinv, b2, out, N, 0);
}